// Round 4
// baseline (201.461 us; speedup 1.0000x reference)
//
#include <hip/hip_runtime.h>

#define N_NODES 100000
#define N_EDGES 2000000

typedef __bf16 bf16x8 __attribute__((ext_vector_type(8)));
typedef float f32x4 __attribute__((ext_vector_type(4)));
typedef float f32x16 __attribute__((ext_vector_type(16)));

__device__ __forceinline__ unsigned f2bf_rne(float f) {
  unsigned u = __builtin_bit_cast(unsigned, f);
  u += 0x7FFFu + ((u >> 16) & 1u);
  return u >> 16;
}

// Pack two NON-NEGATIVE f32 into bf16x2, round-half-up.
__device__ __forceinline__ unsigned pack_rhu(float lo, float hi) {
  unsigned ulo = __builtin_bit_cast(unsigned, lo) + 0x8000u;
  unsigned uhi = __builtin_bit_cast(unsigned, hi) + 0x8000u;
  return __builtin_amdgcn_perm(uhi, ulo, 0x07060302u);
}

// |a-b| on a packed bf16 pair -> packed bf16 pair.
__device__ __forceinline__ unsigned absdiff_pack(unsigned a, unsigned b) {
  float alo = __builtin_bit_cast(float, a << 16);
  float ahi = __builtin_bit_cast(float, a & 0xFFFF0000u);
  float blo = __builtin_bit_cast(float, b << 16);
  float bhi = __builtin_bit_cast(float, b & 0xFFFF0000u);
  return pack_rhu(fabsf(alo - blo), fabsf(ahi - bhi));
}

// ---------------------------------------------------------------------------
// Node MLP via MFMA, grid-stride (proven version, unchanged).
// ---------------------------------------------------------------------------
__global__ __launch_bounds__(64, 1) void node_mfma_kernel(
    const float* __restrict__ X, const float* __restrict__ W1,
    const float* __restrict__ b1, const float* __restrict__ W2,
    const float* __restrict__ b2, unsigned short* __restrict__ H) {
  const int lane = threadIdx.x;
  const int l15 = lane & 15;
  const int quad = lane >> 4;

  float w1v[2][4][8], b1v[2][8];
#pragma unroll
  for (int c = 0; c < 2; ++c)
#pragma unroll
    for (int j = 0; j < 8; ++j) {
      int col = c * 32 + quad * 8 + j;
      b1v[c][j] = b1[col];
#pragma unroll
      for (int d = 0; d < 4; ++d) w1v[c][d][j] = W1[d * 64 + col];
    }

  uint4 afr[2][4];
#pragma unroll
  for (int c = 0; c < 2; ++c)
#pragma unroll
    for (int mt = 0; mt < 4; ++mt) {
      unsigned w[4];
#pragma unroll
      for (int p = 0; p < 4; ++p) {
        int k = c * 32 + quad * 8 + 2 * p;
        unsigned lo = f2bf_rne(W2[k * 64 + mt * 16 + l15]);
        unsigned hi = f2bf_rne(W2[(k + 1) * 64 + mt * 16 + l15]);
        w[p] = lo | (hi << 16);
      }
      afr[c][mt] = make_uint4(w[0], w[1], w[2], w[3]);
    }
  float b2v[16];
#pragma unroll
  for (int mt = 0; mt < 4; ++mt)
#pragma unroll
    for (int r = 0; r < 4; ++r) b2v[mt * 4 + r] = b2[mt * 16 + quad * 4 + r];

  const int ntiles = N_NODES / 16;  // 6250
  for (int tile = blockIdx.x; tile < ntiles; tile += gridDim.x) {
    float4 xv = ((const float4*)X)[tile * 16 + l15];

    uint4 bfr[2];
#pragma unroll
    for (int c = 0; c < 2; ++c) {
      unsigned w[4];
#pragma unroll
      for (int p = 0; p < 4; ++p) {
        float h0 = fmaxf(b1v[c][2 * p] + xv.x * w1v[c][0][2 * p] +
                             xv.y * w1v[c][1][2 * p] + xv.z * w1v[c][2][2 * p] +
                             xv.w * w1v[c][3][2 * p],
                         0.f);
        float h1 = fmaxf(b1v[c][2 * p + 1] + xv.x * w1v[c][0][2 * p + 1] +
                             xv.y * w1v[c][1][2 * p + 1] +
                             xv.z * w1v[c][2][2 * p + 1] +
                             xv.w * w1v[c][3][2 * p + 1],
                         0.f);
        w[p] = pack_rhu(h0, h1);
      }
      bfr[c] = make_uint4(w[0], w[1], w[2], w[3]);
    }

    f32x4 acc[4];
#pragma unroll
    for (int mt = 0; mt < 4; ++mt) acc[mt] = (f32x4){0.f, 0.f, 0.f, 0.f};
#pragma unroll
    for (int c = 0; c < 2; ++c)
#pragma unroll
      for (int mt = 0; mt < 4; ++mt)
        acc[mt] = __builtin_amdgcn_mfma_f32_16x16x32_bf16(
            __builtin_bit_cast(bf16x8, afr[c][mt]),
            __builtin_bit_cast(bf16x8, bfr[c]), acc[mt], 0, 0, 0);

    unsigned short* hrow = H + (tile * 16 + l15) * 64;
#pragma unroll
    for (int mt = 0; mt < 4; ++mt) {
      unsigned lo = pack_rhu(fmaxf(acc[mt][0] + b2v[mt * 4 + 0], 0.f),
                             fmaxf(acc[mt][1] + b2v[mt * 4 + 1], 0.f));
      unsigned hi = pack_rhu(fmaxf(acc[mt][2] + b2v[mt * 4 + 2], 0.f),
                             fmaxf(acc[mt][3] + b2v[mt * 4 + 3], 0.f));
      *(uint2*)(hrow + mt * 16 + quad * 4) = make_uint2(lo, hi);
    }
  }
}

// ---------------------------------------------------------------------------
// Edge MLP v4: direct-to-VGPR gathers + We1 fragments in LDS (shared by all
// waves of the block) -> per-wave registers drop from ~250 to ~165, raising
// occupancy from 2 to 3 waves/SIMD. Round-3 showed the gather latency is
// exposed (MfmaUtil AND VALUBusy both fell vs the LDS-dbuf version); the fix
// is TLP, and the register hog was the per-wave copy of We1^T (104 regs) that
// is identical across waves. Weight frags are now read per tile as 24
// contiguous conflict-free ds_read_b128 (640B/tile/wave -- trivial vs
// 128B/clk/CU LDS bandwidth), interleaved under the MFMAs by the compiler's
// lgkmcnt pipelining.
//
// Bias MFMA chunk removed: be1 is added in the f32 epilogue (algebraically
// identical, numerically identical here since be1=0; saves 2 MFMAs + 8 regs).
// ---------------------------------------------------------------------------
__global__ __launch_bounds__(256, 3) void edge_mlp_kernel(
    const unsigned short* __restrict__ H, const int* __restrict__ pairs,
    const float* __restrict__ We1, const float* __restrict__ be1,
    const float* __restrict__ We2, const float* __restrict__ be2,
    float* __restrict__ out) {
  // We1^T fragments: lds_w[c][mt][lane], identical for every wave. 24 KB.
  __shared__ uint4 lds_w[12][2][64];

  const int tid = threadIdx.x;
  const int lane = tid & 63;
  const int n = lane & 31;     // edge within tile (MFMA col)
  const int half = lane >> 5;  // k-half
  const int wave = tid >> 6;

  // --- Stage We1^T frags to LDS, cooperatively: wave w does chunks 3w..3w+2.
  // lds_w[c][mt][lane] elem j = bf16(We1[(c*16+half*8+j)*64 + mt*32+n]),
  // packed as bf16x2 pairs (same values the old per-wave afr registers held).
#pragma unroll
  for (int ci = 0; ci < 3; ++ci) {
    const int c = wave * 3 + ci;
#pragma unroll
    for (int mt = 0; mt < 2; ++mt) {
      const int col = mt * 32 + n;
      const int kb = c * 16 + half * 8;
      unsigned w[4];
#pragma unroll
      for (int p = 0; p < 4; ++p)
        w[p] = f2bf_rne(We1[(kb + 2 * p) * 64 + col]) |
               (f2bf_rne(We1[(kb + 2 * p + 1) * 64 + col]) << 16);
      lds_w[c][mt][lane] = make_uint4(w[0], w[1], w[2], w[3]);
    }
  }
  __syncthreads();

  // Epilogue constants in registers (one-time global reads):
  // o(mt,r) = mt*32 + (r&3) + 8*(r>>2) + 4*half.
  float we2v[32], be1v[32];
#pragma unroll
  for (int mt = 0; mt < 2; ++mt)
#pragma unroll
    for (int r = 0; r < 16; ++r) {
      const int o = mt * 32 + (r & 3) + 8 * (r >> 2) + 4 * half;
      we2v[mt * 16 + r] = We2[o];
      be1v[mt * 16 + r] = be1[o];
    }
  const float be2v = be2[0];

  const int wid = blockIdx.x * 4 + wave;
  const int nw = gridDim.x * 4;  // 3072
  const int ntiles = N_EDGES / 32;
  const int last = ntiles - 1;
  const int2* pairs2 = (const int2*)pairs;

  // Fold this lane's k-half offset into the H base pointer: the chunk-c
  // fragment for row r is then ((uint4*)(Hh + r*64))[2*c].
  const unsigned short* Hh = H + half * 8;

  // Prologue: gathers for tile wid; pairs for tile wid+nw.
  int2 pr = pairs2[(size_t)wid * 32 + n];
  uint4 hu[4], hv[4];
  {
    const uint4* pu = (const uint4*)(Hh + (size_t)pr.x * 64);
    const uint4* pv = (const uint4*)(Hh + (size_t)pr.y * 64);
#pragma unroll
    for (int c = 0; c < 4; ++c) {
      hu[c] = pu[2 * c];
      hv[c] = pv[2 * c];
    }
  }
  {
    int t1 = wid + nw;
    if (t1 > last) t1 = last;  // clamped prefetch: idempotent, never stored
    pr = pairs2[(size_t)t1 * 32 + n];
  }

  for (int t = wid; t < ntiles; t += nw) {
    // hu/hv hold tile t's B-frags (loads in flight; compiler waits at use).
    uint4 ab[4];
#pragma unroll
    for (int c = 0; c < 4; ++c) {
      ab[c].x = absdiff_pack(hu[c].x, hv[c].x);
      ab[c].y = absdiff_pack(hu[c].y, hv[c].y);
      ab[c].z = absdiff_pack(hu[c].z, hv[c].z);
      ab[c].w = absdiff_pack(hu[c].w, hv[c].w);
    }

    f32x16 acc[2];
    acc[0] = (f32x16)(0.f);
    acc[1] = (f32x16)(0.f);

    // Chunks 0..3: hu. Chunks 4..7: hv. A-frags streamed from LDS.
#pragma unroll
    for (int c = 0; c < 4; ++c) {
      const bf16x8 b = __builtin_bit_cast(bf16x8, hu[c]);
      const uint4 a0 = lds_w[c][0][lane];
      const uint4 a1 = lds_w[c][1][lane];
      acc[0] = __builtin_amdgcn_mfma_f32_32x32x16_bf16(
          __builtin_bit_cast(bf16x8, a0), b, acc[0], 0, 0, 0);
      acc[1] = __builtin_amdgcn_mfma_f32_32x32x16_bf16(
          __builtin_bit_cast(bf16x8, a1), b, acc[1], 0, 0, 0);
    }
#pragma unroll
    for (int c = 0; c < 4; ++c) {
      const bf16x8 b = __builtin_bit_cast(bf16x8, hv[c]);
      const uint4 a0 = lds_w[4 + c][0][lane];
      const uint4 a1 = lds_w[4 + c][1][lane];
      acc[0] = __builtin_amdgcn_mfma_f32_32x32x16_bf16(
          __builtin_bit_cast(bf16x8, a0), b, acc[0], 0, 0, 0);
      acc[1] = __builtin_amdgcn_mfma_f32_32x32x16_bf16(
          __builtin_bit_cast(bf16x8, a1), b, acc[1], 0, 0, 0);
    }

    // hu/hv now dead: issue next tile's gathers into the same registers,
    // then refresh pr for the tile after. Latency hides under the ab MFMAs,
    // epilogue, next-iter absdiff wait, and (now) 3-way wave TLP.
    {
      const uint4* pu = (const uint4*)(Hh + (size_t)pr.x * 64);
      const uint4* pv = (const uint4*)(Hh + (size_t)pr.y * 64);
#pragma unroll
      for (int c = 0; c < 4; ++c) {
        hu[c] = pu[2 * c];
        hv[c] = pv[2 * c];
      }
      int t2 = t + 2 * nw;
      if (t2 > last) t2 = last;
      pr = pairs2[(size_t)t2 * 32 + n];
    }
    __builtin_amdgcn_sched_barrier(0);  // pin gathers before trailing MFMAs

    // Chunks 8..11: |hu-hv|.
#pragma unroll
    for (int c = 0; c < 4; ++c) {
      const bf16x8 b = __builtin_bit_cast(bf16x8, ab[c]);
      const uint4 a0 = lds_w[8 + c][0][lane];
      const uint4 a1 = lds_w[8 + c][1][lane];
      acc[0] = __builtin_amdgcn_mfma_f32_32x32x16_bf16(
          __builtin_bit_cast(bf16x8, a0), b, acc[0], 0, 0, 0);
      acc[1] = __builtin_amdgcn_mfma_f32_32x32x16_bf16(
          __builtin_bit_cast(bf16x8, a1), b, acc[1], 0, 0, 0);
    }

    // Epilogue: bias (be1) + relu + We2 dot, f32. Halves combined via shfl.
    float s = 0.f;
#pragma unroll
    for (int mt = 0; mt < 2; ++mt)
#pragma unroll
      for (int r = 0; r < 16; ++r)
        s += fmaxf(acc[mt][r] + be1v[mt * 16 + r], 0.f) * we2v[mt * 16 + r];
    s += __shfl_xor(s, 32);
    if (half == 0) out[t * 32 + n] = s + be2v;
  }
}

extern "C" void kernel_launch(void* const* d_in, const int* in_sizes, int n_in,
                              void* d_out, int out_size, void* d_ws,
                              size_t ws_size, hipStream_t stream) {
  const float* X = (const float*)d_in[0];
  const int* pairs = (const int*)d_in[1];
  const float* W1 = (const float*)d_in[2];
  const float* b1 = (const float*)d_in[3];
  const float* W2 = (const float*)d_in[4];
  const float* b2 = (const float*)d_in[5];
  const float* We1 = (const float*)d_in[6];
  const float* be1 = (const float*)d_in[7];
  const float* We2 = (const float*)d_in[8];
  const float* be2 = (const float*)d_in[9];
  float* out = (float*)d_out;
  unsigned short* H = (unsigned short*)d_ws;  // 100000*64 bf16 = 12.8 MB

  node_mfma_kernel<<<1024, 64, 0, stream>>>(X, W1, b1, W2, b2, H);
  // 24KB LDS/block; regs target <=168 -> 3 waves/SIMD -> 3 blocks/CU.
  // 768 blocks = exactly resident at 3 blocks/CU x 256 CU.
  edge_mlp_kernel<<<768, 256, 0, stream>>>(H, pairs, We1, be1, We2, be2, out);
}

// Round 5
// 164.898 us; speedup vs baseline: 1.2217x; 1.2217x over previous
//
#include <hip/hip_runtime.h>

#define N_NODES 100000
#define N_EDGES 2000000

typedef __bf16 bf16x8 __attribute__((ext_vector_type(8)));
typedef float f32x4 __attribute__((ext_vector_type(4)));
typedef float f32x16 __attribute__((ext_vector_type(16)));

__device__ __forceinline__ unsigned f2bf_rne(float f) {
  unsigned u = __builtin_bit_cast(unsigned, f);
  u += 0x7FFFu + ((u >> 16) & 1u);
  return u >> 16;
}

// Pack two NON-NEGATIVE f32 into bf16x2, round-half-up.
__device__ __forceinline__ unsigned pack_rhu(float lo, float hi) {
  unsigned ulo = __builtin_bit_cast(unsigned, lo) + 0x8000u;
  unsigned uhi = __builtin_bit_cast(unsigned, hi) + 0x8000u;
  return __builtin_amdgcn_perm(uhi, ulo, 0x07060302u);
}

// |a-b| on a packed bf16 pair -> packed bf16 pair.
__device__ __forceinline__ unsigned absdiff_pack(unsigned a, unsigned b) {
  float alo = __builtin_bit_cast(float, a << 16);
  float ahi = __builtin_bit_cast(float, a & 0xFFFF0000u);
  float blo = __builtin_bit_cast(float, b << 16);
  float bhi = __builtin_bit_cast(float, b & 0xFFFF0000u);
  return pack_rhu(fabsf(alo - blo), fabsf(ahi - bhi));
}

// ---------------------------------------------------------------------------
// Node MLP via MFMA, grid-stride (proven version, unchanged).
// ---------------------------------------------------------------------------
__global__ __launch_bounds__(64, 1) void node_mfma_kernel(
    const float* __restrict__ X, const float* __restrict__ W1,
    const float* __restrict__ b1, const float* __restrict__ W2,
    const float* __restrict__ b2, unsigned short* __restrict__ H) {
  const int lane = threadIdx.x;
  const int l15 = lane & 15;
  const int quad = lane >> 4;

  float w1v[2][4][8], b1v[2][8];
#pragma unroll
  for (int c = 0; c < 2; ++c)
#pragma unroll
    for (int j = 0; j < 8; ++j) {
      int col = c * 32 + quad * 8 + j;
      b1v[c][j] = b1[col];
#pragma unroll
      for (int d = 0; d < 4; ++d) w1v[c][d][j] = W1[d * 64 + col];
    }

  uint4 afr[2][4];
#pragma unroll
  for (int c = 0; c < 2; ++c)
#pragma unroll
    for (int mt = 0; mt < 4; ++mt) {
      unsigned w[4];
#pragma unroll
      for (int p = 0; p < 4; ++p) {
        int k = c * 32 + quad * 8 + 2 * p;
        unsigned lo = f2bf_rne(W2[k * 64 + mt * 16 + l15]);
        unsigned hi = f2bf_rne(W2[(k + 1) * 64 + mt * 16 + l15]);
        w[p] = lo | (hi << 16);
      }
      afr[c][mt] = make_uint4(w[0], w[1], w[2], w[3]);
    }
  float b2v[16];
#pragma unroll
  for (int mt = 0; mt < 4; ++mt)
#pragma unroll
    for (int r = 0; r < 4; ++r) b2v[mt * 4 + r] = b2[mt * 16 + quad * 4 + r];

  const int ntiles = N_NODES / 16;  // 6250
  for (int tile = blockIdx.x; tile < ntiles; tile += gridDim.x) {
    float4 xv = ((const float4*)X)[tile * 16 + l15];

    uint4 bfr[2];
#pragma unroll
    for (int c = 0; c < 2; ++c) {
      unsigned w[4];
#pragma unroll
      for (int p = 0; p < 4; ++p) {
        float h0 = fmaxf(b1v[c][2 * p] + xv.x * w1v[c][0][2 * p] +
                             xv.y * w1v[c][1][2 * p] + xv.z * w1v[c][2][2 * p] +
                             xv.w * w1v[c][3][2 * p],
                         0.f);
        float h1 = fmaxf(b1v[c][2 * p + 1] + xv.x * w1v[c][0][2 * p + 1] +
                             xv.y * w1v[c][1][2 * p + 1] +
                             xv.z * w1v[c][2][2 * p + 1] +
                             xv.w * w1v[c][3][2 * p + 1],
                         0.f);
        w[p] = pack_rhu(h0, h1);
      }
      bfr[c] = make_uint4(w[0], w[1], w[2], w[3]);
    }

    f32x4 acc[4];
#pragma unroll
    for (int mt = 0; mt < 4; ++mt) acc[mt] = (f32x4){0.f, 0.f, 0.f, 0.f};
#pragma unroll
    for (int c = 0; c < 2; ++c)
#pragma unroll
      for (int mt = 0; mt < 4; ++mt)
        acc[mt] = __builtin_amdgcn_mfma_f32_16x16x32_bf16(
            __builtin_bit_cast(bf16x8, afr[c][mt]),
            __builtin_bit_cast(bf16x8, bfr[c]), acc[mt], 0, 0, 0);

    unsigned short* hrow = H + (tile * 16 + l15) * 64;
#pragma unroll
    for (int mt = 0; mt < 4; ++mt) {
      unsigned lo = pack_rhu(fmaxf(acc[mt][0] + b2v[mt * 4 + 0], 0.f),
                             fmaxf(acc[mt][1] + b2v[mt * 4 + 1], 0.f));
      unsigned hi = pack_rhu(fmaxf(acc[mt][2] + b2v[mt * 4 + 2], 0.f),
                             fmaxf(acc[mt][3] + b2v[mt * 4 + 3], 0.f));
      *(uint2*)(hrow + mt * 16 + quad * 4) = make_uint2(lo, hi);
    }
  }
}

// ---------------------------------------------------------------------------
// Edge MLP v5: direct-to-VGPR gathers + depth-2 REGISTER double buffer +
// all wave-invariant constants in LDS.
//
// Round-4 post-mortem: __launch_bounds__(256,3) + 64 regs of per-lane
// epilogue constants made the allocator spill to scratch (FETCH +143MB,
// WRITE +16MB, VGPR_Count=84). Fix: be1/We2 live in 512B of LDS (broadcast
// ds_read_b128 per tile), We1^T frags stay in 24KB LDS. Arch-VGPR demand
// ~120 + 32 AGPR acc -> fits 3 waves/SIMD without spill.
//
// Round-3 post-mortem: single-buffer direct gathers exposed latency
// (prefetch distance ~150cyc < ~400cyc gather latency). Fix: two named
// register buffers (A/B, static indexing); body(t) consumes CUR and refills
// CUR for t+2*nw right after its last MFMA use -> prefetch distance = one
// full tile of compute (ab MFMAs + epilogue + next body's absdiff+hu/hv
// MFMAs), like the proven round-0 LDS schedule but with zero LDS traffic
// for the gathered rows and zero bank conflicts.
//
// Tail: all prefetch tile indices clamp to `last`; an overrun body
// recomputes tile `last` from identical inputs and rewrites the identical
// value (benign, same scheme as the proven round-0 kernel).
// ---------------------------------------------------------------------------
__global__ __launch_bounds__(256, 3) void edge_mlp_kernel(
    const unsigned short* __restrict__ H, const int* __restrict__ pairs,
    const float* __restrict__ We1, const float* __restrict__ be1,
    const float* __restrict__ We2, const float* __restrict__ be2,
    float* __restrict__ out) {
  // We1^T fragments, identical for every wave: 24 KB.
  __shared__ uint4 lds_w[12][2][64];
  // Epilogue constants: lds_c[0][o]=be1[o], lds_c[1][o]=We2[o]. 512 B.
  __shared__ float lds_c[2][64];

  const int tid = threadIdx.x;
  const int lane = tid & 63;
  const int n = lane & 31;     // edge within tile (MFMA col)
  const int half = lane >> 5;  // k-half
  const int wave = tid >> 6;

  // --- Stage We1^T frags to LDS, cooperatively: wave w does chunks 3w..3w+2.
  // lds_w[c][mt][lane] elem j = bf16(We1[(c*16+half*8+j)*64 + mt*32+n]).
#pragma unroll
  for (int ci = 0; ci < 3; ++ci) {
    const int c = wave * 3 + ci;
#pragma unroll
    for (int mt = 0; mt < 2; ++mt) {
      const int col = mt * 32 + n;
      const int kb = c * 16 + half * 8;
      unsigned w[4];
#pragma unroll
      for (int p = 0; p < 4; ++p)
        w[p] = f2bf_rne(We1[(kb + 2 * p) * 64 + col]) |
               (f2bf_rne(We1[(kb + 2 * p + 1) * 64 + col]) << 16);
      lds_w[c][mt][lane] = make_uint4(w[0], w[1], w[2], w[3]);
    }
  }
  if (tid < 64) {
    lds_c[0][tid] = be1[tid];
    lds_c[1][tid] = We2[tid];
  }
  __syncthreads();

  const float be2v = be2[0];

  const int wid = blockIdx.x * 4 + wave;
  const int nw = gridDim.x * 4;  // 3072
  const int ntiles = N_EDGES / 32;
  const int last = ntiles - 1;
  const int2* pairs2 = (const int2*)pairs;

  // Fold this lane's k-half offset into the H base pointer: the chunk-c
  // fragment for row r is then ((uint4*)(Hh + r*64))[2*c].
  const unsigned short* Hh = H + half * 8;

  // Rolling pair registers: at entry to body(t), pr = pairs(min(t+2nw,last)).
  int2 pr;
  uint4 huA[4], hvA[4], huB[4], hvB[4];

  // Prologue: fill A with tile wid, B with tile min(wid+nw,last).
  pr = pairs2[(size_t)wid * 32 + n];
  {
    const uint4* pu = (const uint4*)(Hh + (size_t)pr.x * 64);
    const uint4* pv = (const uint4*)(Hh + (size_t)pr.y * 64);
#pragma unroll
    for (int c = 0; c < 4; ++c) {
      huA[c] = pu[2 * c];
      hvA[c] = pv[2 * c];
    }
  }
  {
    int t1 = wid + nw;
    if (t1 > last) t1 = last;
    pr = pairs2[(size_t)t1 * 32 + n];
  }
  {
    const uint4* pu = (const uint4*)(Hh + (size_t)pr.x * 64);
    const uint4* pv = (const uint4*)(Hh + (size_t)pr.y * 64);
#pragma unroll
    for (int c = 0; c < 4; ++c) {
      huB[c] = pu[2 * c];
      hvB[c] = pv[2 * c];
    }
  }
  {
    int t2 = wid + 2 * nw;
    if (t2 > last) t2 = last;
    pr = pairs2[(size_t)t2 * 32 + n];
  }

  // One tile: consume (hu,hv) = tile min(t,last); refill them with tile
  // min(t+2nw,last) right after their last MFMA use; pr -> min(t+3nw,last).
  auto body = [&](int t, uint4(&hu)[4], uint4(&hv)[4]) {
    const int tt = t <= last ? t : last;

    // absdiff first: this is where the wave waits for this buffer's loads
    // (the other buffer's 8 loads + pairs stay outstanding -> partial vmcnt).
    uint4 ab[4];
#pragma unroll
    for (int c = 0; c < 4; ++c) {
      ab[c].x = absdiff_pack(hu[c].x, hv[c].x);
      ab[c].y = absdiff_pack(hu[c].y, hv[c].y);
      ab[c].z = absdiff_pack(hu[c].z, hv[c].z);
      ab[c].w = absdiff_pack(hu[c].w, hv[c].w);
    }

    f32x16 acc[2];
    acc[0] = (f32x16)(0.f);
    acc[1] = (f32x16)(0.f);

    // Chunks 0..3: hu. Chunks 4..7: hv. A-frags streamed from LDS.
#pragma unroll
    for (int c = 0; c < 4; ++c) {
      const bf16x8 b = __builtin_bit_cast(bf16x8, hu[c]);
      const uint4 a0 = lds_w[c][0][lane];
      const uint4 a1 = lds_w[c][1][lane];
      acc[0] = __builtin_amdgcn_mfma_f32_32x32x16_bf16(
          __builtin_bit_cast(bf16x8, a0), b, acc[0], 0, 0, 0);
      acc[1] = __builtin_amdgcn_mfma_f32_32x32x16_bf16(
          __builtin_bit_cast(bf16x8, a1), b, acc[1], 0, 0, 0);
    }
#pragma unroll
    for (int c = 0; c < 4; ++c) {
      const bf16x8 b = __builtin_bit_cast(bf16x8, hv[c]);
      const uint4 a0 = lds_w[4 + c][0][lane];
      const uint4 a1 = lds_w[4 + c][1][lane];
      acc[0] = __builtin_amdgcn_mfma_f32_32x32x16_bf16(
          __builtin_bit_cast(bf16x8, a0), b, acc[0], 0, 0, 0);
      acc[1] = __builtin_amdgcn_mfma_f32_32x32x16_bf16(
          __builtin_bit_cast(bf16x8, a1), b, acc[1], 0, 0, 0);
    }

    // hu/hv dead: refill THIS buffer for tile min(t+2nw,last); then advance
    // pr. Prefetch distance = ab-MFMAs + epilogue + next body's front half.
    {
      const uint4* pu = (const uint4*)(Hh + (size_t)pr.x * 64);
      const uint4* pv = (const uint4*)(Hh + (size_t)pr.y * 64);
#pragma unroll
      for (int c = 0; c < 4; ++c) {
        hu[c] = pu[2 * c];
        hv[c] = pv[2 * c];
      }
      int t3 = t + 3 * nw;
      if (t3 > last) t3 = last;
      pr = pairs2[(size_t)t3 * 32 + n];
    }
    __builtin_amdgcn_sched_barrier(0);  // pin gather issue before ab MFMAs

    // Chunks 8..11: |hu-hv|.
#pragma unroll
    for (int c = 0; c < 4; ++c) {
      const bf16x8 b = __builtin_bit_cast(bf16x8, ab[c]);
      const uint4 a0 = lds_w[8 + c][0][lane];
      const uint4 a1 = lds_w[8 + c][1][lane];
      acc[0] = __builtin_amdgcn_mfma_f32_32x32x16_bf16(
          __builtin_bit_cast(bf16x8, a0), b, acc[0], 0, 0, 0);
      acc[1] = __builtin_amdgcn_mfma_f32_32x32x16_bf16(
          __builtin_bit_cast(bf16x8, a1), b, acc[1], 0, 0, 0);
    }

    // Epilogue: bias + relu + We2 dot in f32; constants broadcast from LDS.
    // acc row index: o = mt*32 + q + 8*g + 4*half, with acc[mt][4g+q].
    float s = 0.f;
#pragma unroll
    for (int mt = 0; mt < 2; ++mt)
#pragma unroll
      for (int g = 0; g < 4; ++g) {
        const int o = mt * 32 + g * 8 + 4 * half;
        const float4 eb = *(const float4*)&lds_c[0][o];
        const float4 ew = *(const float4*)&lds_c[1][o];
        s += fmaxf(acc[mt][4 * g + 0] + eb.x, 0.f) * ew.x;
        s += fmaxf(acc[mt][4 * g + 1] + eb.y, 0.f) * ew.y;
        s += fmaxf(acc[mt][4 * g + 2] + eb.z, 0.f) * ew.z;
        s += fmaxf(acc[mt][4 * g + 3] + eb.w, 0.f) * ew.w;
      }
    s += __shfl_xor(s, 32);
    if (half == 0) out[tt * 32 + n] = s + be2v;
  };

  for (int t = wid; t < ntiles; t += 2 * nw) {
    body(t, huA, hvA);
    body(t + nw, huB, hvB);
  }
}

extern "C" void kernel_launch(void* const* d_in, const int* in_sizes, int n_in,
                              void* d_out, int out_size, void* d_ws,
                              size_t ws_size, hipStream_t stream) {
  const float* X = (const float*)d_in[0];
  const int* pairs = (const int*)d_in[1];
  const float* W1 = (const float*)d_in[2];
  const float* b1 = (const float*)d_in[3];
  const float* W2 = (const float*)d_in[4];
  const float* b2 = (const float*)d_in[5];
  const float* We1 = (const float*)d_in[6];
  const float* be1 = (const float*)d_in[7];
  const float* We2 = (const float*)d_in[8];
  const float* be2 = (const float*)d_in[9];
  float* out = (float*)d_out;
  unsigned short* H = (unsigned short*)d_ws;  // 100000*64 bf16 = 12.8 MB

  node_mfma_kernel<<<1024, 64, 0, stream>>>(X, W1, b1, W2, b2, H);
  // 24.5KB LDS/block, ~155 total regs/wave -> 3 blocks/CU, 3 waves/SIMD.
  // 768 blocks = exactly resident.
  edge_mlp_kernel<<<768, 256, 0, stream>>>(H, pairs, We1, be1, We2, be2, out);
}